// Round 4
// baseline (595.873 us; speedup 1.0000x reference)
//
#include <hip/hip_runtime.h>

typedef unsigned short u16;
typedef __bf16 bf16x8 __attribute__((ext_vector_type(8)));
typedef float f32x4 __attribute__((ext_vector_type(4)));

// Problem constants: B=8, N=2048, DH=512
#define SEQN 2048
#define DHID 512

static __device__ __forceinline__ float bf2f(u16 u) {
    union { unsigned int i; float f; } c; c.i = ((unsigned int)u) << 16; return c.f;
}
static __device__ __forceinline__ u16 f2bf(float f) {
    union { float f; unsigned int i; } c; c.f = f;
    unsigned int x = c.i;
    return (u16)((x + 0x7fffu + ((x >> 16) & 1u)) >> 16);
}

// async global->LDS, 16B per lane, LDS dest = wave-uniform base + lane*16
static __device__ __forceinline__ void gld_lds16(const u16* g, u16* l) {
    __builtin_amdgcn_global_load_lds(
        (__attribute__((address_space(1))) void*)(g),
        (__attribute__((address_space(3))) void*)(l), 16, 0, 0);
}

// ---------------------------------------------------------------------------
// fp32 -> bf16 conversion (n multiple of 8)
// ---------------------------------------------------------------------------
__global__ __launch_bounds__(256) void cvt_kernel(const float* __restrict__ src,
                                                  u16* __restrict__ dst, int n) {
    int i = (blockIdx.x * 256 + threadIdx.x) * 8;
    if (i >= n) return;
    float4 a = *(const float4*)(src + i);
    float4 b = *(const float4*)(src + i + 4);
    union { uint4 u; u16 s[8]; } o;
    o.s[0] = f2bf(a.x); o.s[1] = f2bf(a.y); o.s[2] = f2bf(a.z); o.s[3] = f2bf(a.w);
    o.s[4] = f2bf(b.x); o.s[5] = f2bf(b.y); o.s[6] = f2bf(b.z); o.s[7] = f2bf(b.w);
    *(uint4*)(dst + i) = o.u;
}

// fp32 [K][N] -> bf16 transposed [N][K]
__global__ __launch_bounds__(256) void cvt_t_kernel(const float* __restrict__ src,
                                                    u16* __restrict__ dst, int K, int N) {
    int idx = blockIdx.x * 256 + threadIdx.x;
    if (idx >= K * N) return;
    int n = idx / K, k = idx - n * K;
    dst[idx] = f2bf(src[(size_t)k * N + n]);
}

// ---------------------------------------------------------------------------
// hop_emb row means (fp32 in): hm[j] = mean_d hop_emb[j][d]
// ---------------------------------------------------------------------------
__global__ void hmean_kernel(const float* __restrict__ hop, float* __restrict__ hm) {
    int j = blockIdx.x, t = threadIdx.x;           // 64 threads
    const float* p = hop + (size_t)j * DHID + t * 8;
    float4 a = *(const float4*)p;
    float4 b = *(const float4*)(p + 4);
    float s = a.x + a.y + a.z + a.w + b.x + b.y + b.z + b.w;
#pragma unroll
    for (int m = 1; m < 64; m <<= 1) s += __shfl_xor(s, m);
    if (t == 0) hm[j] = s * (1.0f / (float)DHID);
}

// ---------------------------------------------------------------------------
// BT MFMA GEMM: C[M,N] = A[M,K] * Bt[N,K]^T + epilogue  (A,Bt,C bf16)
// Tile 128x128x32, 256 threads (4 waves as 2x2 of 64x64), 16x16x32 MFMA.
// ---------------------------------------------------------------------------
enum { EPI_BIAS = 0, EPI_RELU = 1, EPI_PLAIN = 3, EPI_BIAS_T = 4 };

template <int EPI>
__global__ __launch_bounds__(256) void gemm_bt(
    const u16* __restrict__ A, const u16* __restrict__ Bt, u16* __restrict__ C,
    const float* __restrict__ bias,
    int K, int lda, int ldb, int ldc,
    long sA, long sB, long sC)
{
    __shared__ u16 As[128 * 32];   // 8 KB, [row][k], row stride 64 B
    __shared__ u16 Bs[128 * 32];   // 8 KB, [n][k]

    const int tid = threadIdx.x;
    const int bz = blockIdx.z;
    const u16* Ab = A + (size_t)bz * sA;
    const u16* Bb = Bt + (size_t)bz * sB;
    u16* Cb = C + (size_t)bz * sC;

    const int bm0 = blockIdx.y * 128, bn0 = blockIdx.x * 128;
    const int wid = tid >> 6, lane = tid & 63, quad = lane >> 4, l16 = lane & 15;
    const int wm = (wid >> 1) * 64, wn = (wid & 1) * 64;
    const int srow = lane >> 2;            // 0..15: row within 16-row chunk
    const int skof = (lane & 3) * 8;       // k element offset (8 bf16 = 16 B)

    f32x4 acc[4][4];
#pragma unroll
    for (int i = 0; i < 4; ++i)
#pragma unroll
        for (int j = 0; j < 4; ++j) acc[i][j] = (f32x4){0.f, 0.f, 0.f, 0.f};

    for (int k0 = 0; k0 < K; k0 += 32) {
#pragma unroll
        for (int it = 0; it < 2; ++it) {
            int c = wid * 2 + it;          // wave-uniform
            gld_lds16(Ab + (size_t)(bm0 + c * 16 + srow) * lda + k0 + skof,
                      &As[c * 512]);
        }
#pragma unroll
        for (int it = 0; it < 2; ++it) {
            int c = wid * 2 + it;
            gld_lds16(Bb + (size_t)(bn0 + c * 16 + srow) * ldb + k0 + skof,
                      &Bs[c * 512]);
        }
        __syncthreads();

        bf16x8 af[4], bfr[4];
#pragma unroll
        for (int i = 0; i < 4; ++i)
            af[i] = *(const bf16x8*)&As[(wm + i * 16 + l16) * 32 + quad * 8];
#pragma unroll
        for (int j = 0; j < 4; ++j)
            bfr[j] = *(const bf16x8*)&Bs[(wn + j * 16 + l16) * 32 + quad * 8];
#pragma unroll
        for (int i = 0; i < 4; ++i)
#pragma unroll
            for (int j = 0; j < 4; ++j)
                acc[i][j] = __builtin_amdgcn_mfma_f32_16x16x32_bf16(af[i], bfr[j], acc[i][j], 0, 0, 0);
        __syncthreads();
    }

#pragma unroll
    for (int i = 0; i < 4; ++i) {
#pragma unroll
        for (int j = 0; j < 4; ++j) {
            const int gn = bn0 + wn + j * 16 + l16;
            const int gm0 = bm0 + wm + i * 16 + quad * 4;
            if constexpr (EPI == EPI_BIAS || EPI == EPI_RELU) {
                const float b = bias[gn];
#pragma unroll
                for (int r = 0; r < 4; ++r) {
                    float v = acc[i][j][r] + b;
                    if constexpr (EPI == EPI_RELU) v = fmaxf(v, 0.f);
                    Cb[(size_t)(gm0 + r) * ldc + gn] = f2bf(v);
                }
            } else if constexpr (EPI == EPI_BIAS_T) {
                // write transposed: Ct[b][col][row], per-batch [512][2048]
                const float b = bias[gn];
                const int bb = gm0 >> 11, n = gm0 & 2047;
                ushort4 o;
                o.x = f2bf(acc[i][j][0] + b);
                o.y = f2bf(acc[i][j][1] + b);
                o.z = f2bf(acc[i][j][2] + b);
                o.w = f2bf(acc[i][j][3] + b);
                *(ushort4*)&C[((size_t)bb * 512 + gn) * 2048 + n] = o;
            } else {
#pragma unroll
                for (int r = 0; r < 4; ++r)
                    Cb[(size_t)(gm0 + r) * ldc + gn] = f2bf(acc[i][j][r]);
            }
        }
    }
}

// ---------------------------------------------------------------------------
// Fused attention: per block = one batch (blockIdx.x) x 64 Q-rows (blockIdx.y*64).
// 4 waves, wave w owns Q-rows [q0+16w, q0+16w+16).
// Loops 32-wide KV tiles: S=QK^T (MFMA) -> exp(s*scale*adj*hm) (no max needed,
// |s'|<~0.3) -> row-sum accumulate -> LDS transpose -> O += P@V (MFMA).
// Final: O /= rowsum.  LDS: Ks 32KB [ds16][kv32][d32] | Vs 32KB [d512][kv32];
// P (16x40 u16 per wave) reuses Ks region after barrier.
// ---------------------------------------------------------------------------
__global__ __launch_bounds__(256, 1) void attn_kernel(
    const u16* __restrict__ Q, const u16* __restrict__ K, const u16* __restrict__ Vt,
    const float* __restrict__ adj, const float* __restrict__ hm,
    u16* __restrict__ AO)
{
    extern __shared__ u16 lds[];                 // 65536 B
    u16* Ks = lds;                               // 16384 u16
    u16* Vs = lds + 16384;                       // 16384 u16

    const int tid = threadIdx.x, wid = tid >> 6, lane = tid & 63;
    const int quad = lane >> 4, l16 = lane & 15;
    const int b = blockIdx.x;                    // batch -> XCD = b (L2 locality)
    const int q0w = blockIdx.y * 64 + wid * 16;  // wave's 16 Q-rows
    const int srow = lane >> 2, sko = (lane & 3) * 8;

    const u16* Qg = Q + (size_t)b * SEQN * DHID;
    const u16* Kg = K + (size_t)b * SEQN * DHID;
    const u16* Vg = Vt + (size_t)b * DHID * SEQN;
    const float* adjg = adj + (size_t)b * SEQN * SEQN;
    u16* AOg = AO + (size_t)b * SEQN * DHID;
    u16* Plds = lds + wid * 640;                 // 16 rows x 40 u16, inside Ks region

    const float scale = 0.044194173824159216f;   // 1/sqrt(512)

    // Q fragments in registers: A-layout qf[ds]: lane holds Q[q0w+l16][ds*32+quad*8+j]
    bf16x8 qf[16];
#pragma unroll
    for (int ds = 0; ds < 16; ++ds)
        qf[ds] = *(const bf16x8*)(Qg + (size_t)(q0w + l16) * DHID + ds * 32 + quad * 8);

    f32x4 oacc[32];
#pragma unroll
    for (int dt = 0; dt < 32; ++dt) oacc[dt] = (f32x4){0.f, 0.f, 0.f, 0.f};
    float lsum[4] = {0.f, 0.f, 0.f, 0.f};

    for (int kt = 0; kt < 64; ++kt) {
        const int kv0 = kt * 32;

        // ---- stage Ks [ds][kv 16c..16c+16)[d32]: chunk id = wid*8+i ----
#pragma unroll
        for (int i = 0; i < 8; ++i) {
            int id = wid * 8 + i;                // wave-uniform
            int ds = id >> 1, c = id & 1;
            gld_lds16(Kg + (size_t)(kv0 + c * 16 + srow) * DHID + ds * 32 + sko,
                      &Ks[ds * 1024 + c * 512]);
        }
        __syncthreads();                         // Ks ready (vmcnt drained)

        // ---- stage Vs async (needed only in PV phase) ----
#pragma unroll
        for (int i = 0; i < 8; ++i) {
            int id = wid * 8 + i;                // d-rows id*16..id*16+16
            gld_lds16(Vg + (size_t)(id * 16 + srow) * SEQN + kv0 + sko,
                      &Vs[id * 512]);
        }

        // ---- early scalar loads (hide HBM latency under QK^T) ----
        float hv0 = hm[kv0 + l16] * scale;
        float hv1 = hm[kv0 + 16 + l16] * scale;
        float av[8];
        const float* arow = adjg + (size_t)(q0w + quad * 4) * SEQN + kv0;
#pragma unroll
        for (int r = 0; r < 4; ++r) {
            av[r]     = arow[(size_t)r * SEQN + l16];
            av[4 + r] = arow[(size_t)r * SEQN + 16 + l16];
        }

        // ---- QK^T: S 16x32, 4 independent chains ----
        f32x4 s0a = {0.f,0.f,0.f,0.f}, s0b = {0.f,0.f,0.f,0.f};
        f32x4 s1a = {0.f,0.f,0.f,0.f}, s1b = {0.f,0.f,0.f,0.f};
#pragma unroll
        for (int ds = 0; ds < 16; ds += 2) {
            bf16x8 k00 = *(const bf16x8*)&Ks[ds * 1024 + l16 * 32 + quad * 8];
            bf16x8 k01 = *(const bf16x8*)&Ks[ds * 1024 + 512 + l16 * 32 + quad * 8];
            s0a = __builtin_amdgcn_mfma_f32_16x16x32_bf16(qf[ds], k00, s0a, 0, 0, 0);
            s1a = __builtin_amdgcn_mfma_f32_16x16x32_bf16(qf[ds], k01, s1a, 0, 0, 0);
            bf16x8 k10 = *(const bf16x8*)&Ks[(ds + 1) * 1024 + l16 * 32 + quad * 8];
            bf16x8 k11 = *(const bf16x8*)&Ks[(ds + 1) * 1024 + 512 + l16 * 32 + quad * 8];
            s0b = __builtin_amdgcn_mfma_f32_16x16x32_bf16(qf[ds + 1], k10, s0b, 0, 0, 0);
            s1b = __builtin_amdgcn_mfma_f32_16x16x32_bf16(qf[ds + 1], k11, s1b, 0, 0, 0);
        }
        f32x4 s0 = s0a + s0b, s1 = s1a + s1b;
        __syncthreads();                         // all waves done reading Ks; Vs drained

        // ---- P = exp(s'), row-sum, write to LDS in A-layout position ----
#pragma unroll
        for (int r = 0; r < 4; ++r) {
            float p0 = __expf(s0[r] * av[r] * hv0);
            float p1 = __expf(s1[r] * av[4 + r] * hv1);
            lsum[r] += p0 + p1;
            Plds[(quad * 4 + r) * 40 + l16] = f2bf(p0);
            Plds[(quad * 4 + r) * 40 + 16 + l16] = f2bf(p1);
        }
        asm volatile("s_waitcnt lgkmcnt(0)" ::: "memory");

        // ---- PV: O[16x512] += P[16x32] @ V[32x512] ----
        bf16x8 pf = *(const bf16x8*)&Plds[l16 * 40 + quad * 8];
#pragma unroll
        for (int dt = 0; dt < 32; ++dt) {
            bf16x8 vf = *(const bf16x8*)&Vs[(dt * 16 + l16) * 32 + quad * 8];
            oacc[dt] = __builtin_amdgcn_mfma_f32_16x16x32_bf16(pf, vf, oacc[dt], 0, 0, 0);
        }
        __syncthreads();                         // done reading P/Vs before restage
    }

    // ---- finalize: reduce row sums over l16 group, divide, store ----
#pragma unroll
    for (int r = 0; r < 4; ++r) {
#pragma unroll
        for (int m = 1; m < 16; m <<= 1) lsum[r] += __shfl_xor(lsum[r], m);
        lsum[r] = 1.f / lsum[r];
    }
#pragma unroll
    for (int dt = 0; dt < 32; ++dt) {
#pragma unroll
        for (int r = 0; r < 4; ++r) {
            AOg[(size_t)(q0w + quad * 4 + r) * DHID + dt * 16 + l16] =
                f2bf(oacc[dt][r] * lsum[r]);
        }
    }
}

// ---------------------------------------------------------------------------
// LayerNorm over last dim (512): out = LN(a + b) * g + be
// ---------------------------------------------------------------------------
template <bool B_F32, bool OUT_F32>
__global__ __launch_bounds__(256) void ln_kernel(
    const u16* __restrict__ a, const void* __restrict__ bp,
    const float* __restrict__ g, const float* __restrict__ be,
    void* __restrict__ out)
{
    size_t row = blockIdx.x;
    int t = threadIdx.x, wid = t >> 6, lane = t & 63;
    const u16* pa = a + row * (size_t)DHID;

    unsigned int va = *(const unsigned int*)(pa + t * 2);
    float b0, b1;
    if constexpr (B_F32) {
        float2 vb = *(const float2*)((const float*)bp + row * (size_t)DHID + t * 2);
        b0 = vb.x; b1 = vb.y;
    } else {
        unsigned int vb = *(const unsigned int*)((const u16*)bp + row * (size_t)DHID + t * 2);
        b0 = bf2f((u16)(vb & 0xffff)); b1 = bf2f((u16)(vb >> 16));
    }
    float x0 = bf2f((u16)(va & 0xffff)) + b0;
    float x1 = bf2f((u16)(va >> 16)) + b1;
    float s = x0 + x1, sq = x0 * x0 + x1 * x1;
#pragma unroll
    for (int m = 1; m < 64; m <<= 1) { s += __shfl_xor(s, m); sq += __shfl_xor(sq, m); }
    __shared__ float rs[4], rq[4];
    if (lane == 0) { rs[wid] = s; rq[wid] = sq; }
    __syncthreads();
    s = rs[0] + rs[1] + rs[2] + rs[3];
    sq = rq[0] + rq[1] + rq[2] + rq[3];
    float mean = s * (1.f / (float)DHID);
    float var = sq * (1.f / (float)DHID) - mean * mean;
    float rstd = rsqrtf(var + 1e-5f);

    float2 vg = *(const float2*)(g + t * 2);
    float2 vbe = *(const float2*)(be + t * 2);
    float y0 = (x0 - mean) * rstd * vg.x + vbe.x;
    float y1 = (x1 - mean) * rstd * vg.y + vbe.y;
    if constexpr (OUT_F32) {
        *(float2*)((float*)out + row * (size_t)DHID + t * 2) = make_float2(y0, y1);
    } else {
        unsigned int o = (unsigned int)f2bf(y0) | ((unsigned int)f2bf(y1) << 16);
        *(unsigned int*)((u16*)out + row * (size_t)DHID + t * 2) = o;
    }
}

// ---------------------------------------------------------------------------
extern "C" void kernel_launch(void* const* d_in, const int* in_sizes, int n_in,
                              void* d_out, int out_size, void* d_ws, size_t ws_size,
                              hipStream_t stream) {
    const float* H   = (const float*)d_in[0];
    const float* adj = (const float*)d_in[1];
    const float* hop = (const float*)d_in[2];
    const float* Wq  = (const float*)d_in[3];
    const float* bq  = (const float*)d_in[4];
    const float* Wk  = (const float*)d_in[5];
    const float* bk  = (const float*)d_in[6];
    const float* Wv  = (const float*)d_in[7];
    const float* bv  = (const float*)d_in[8];
    const float* W1  = (const float*)d_in[9];
    const float* b1  = (const float*)d_in[10];
    const float* W2  = (const float*)d_in[11];
    const float* b2  = (const float*)d_in[12];
    const float* g1  = (const float*)d_in[13];
    const float* be1 = (const float*)d_in[14];
    const float* g2  = (const float*)d_in[15];
    const float* be2 = (const float*)d_in[16];

    const size_t MiB = 1ull << 20;
    char* w = (char*)d_ws;
    float* hm  = (float*)w;                       // 8 KB
    u16* Hb   = (u16*)(w + 1 * MiB);              // 16 MiB
    u16* Wqt  = (u16*)(w + 17 * MiB);             // 0.5 MiB each
    u16* Wkt  = (u16*)(w + 17 * MiB + 512 * 1024);
    u16* Wvt  = (u16*)(w + 18 * MiB);
    u16* W1t  = (u16*)(w + 18 * MiB + 512 * 1024);// 1 MiB
    u16* W2t  = (u16*)(w + 19 * MiB + 512 * 1024);// 1 MiB
    u16* Q    = (u16*)(w + 21 * MiB);             // 16 MiB
    u16* Kb   = (u16*)(w + 37 * MiB);             // 16 MiB
    u16* Vt   = (u16*)(w + 53 * MiB);             // 16 MiB  [b][512][2048]
    u16* AO   = (u16*)(w + 69 * MiB);             // 16 MiB
    u16* HID  = (u16*)(w + 85 * MiB);             // 32 MiB -> total 117 MiB
    // aliases (lifetimes disjoint):
    u16* X   = Kb;   // LN1 output (K dead after attention)
    u16* F2  = Vt;   // ffn2 output (V dead after attention)

    const int BN = 8, N = SEQN, D = DHID;
    const long nd = (long)N * D;

    // fp32 -> bf16 conversions (weights transposed)
    cvt_kernel<<<(BN * N * D) / (8 * 256), 256, 0, stream>>>(H, Hb, BN * N * D);
    cvt_t_kernel<<<(D * D + 255) / 256, 256, 0, stream>>>(Wq, Wqt, D, D);
    cvt_t_kernel<<<(D * D + 255) / 256, 256, 0, stream>>>(Wk, Wkt, D, D);
    cvt_t_kernel<<<(D * D + 255) / 256, 256, 0, stream>>>(Wv, Wvt, D, D);
    cvt_t_kernel<<<(D * 2 * D + 255) / 256, 256, 0, stream>>>(W1, W1t, D, 2 * D);
    cvt_t_kernel<<<(2 * D * D + 255) / 256, 256, 0, stream>>>(W2, W2t, 2 * D, D);

    hmean_kernel<<<N, 64, 0, stream>>>(hop, hm);

    // Q,K = H @ W + b ; V written transposed [b][512][2048]
    gemm_bt<EPI_BIAS><<<dim3(4, 128, 1), 256, 0, stream>>>(
        Hb, Wqt, Q, bq, D, D, D, D, 0, 0, 0);
    gemm_bt<EPI_BIAS><<<dim3(4, 128, 1), 256, 0, stream>>>(
        Hb, Wkt, Kb, bk, D, D, D, D, 0, 0, 0);
    gemm_bt<EPI_BIAS_T><<<dim3(4, 128, 1), 256, 0, stream>>>(
        Hb, Wvt, Vt, bv, D, D, D, D, 0, 0, 0);

    // fused attention: grid (batch=8 -> XCD affinity, 32 Q-stripes)
    attn_kernel<<<dim3(8, 32), 256, 65536, stream>>>(Q, Kb, Vt, adj, hm, AO);

    // x = LN(attn_out + H)   (H fp32)
    ln_kernel<true, false><<<BN * N, 256, 0, stream>>>(AO, H, g1, be1, X);

    // hid = relu(x @ W1 + b1)
    gemm_bt<EPI_RELU><<<dim3(8, 128, 1), 256, 0, stream>>>(
        X, W1t, HID, b1, D, D, D, 2 * D, 0, 0, 0);

    // f2 = hid @ W2 + b2
    gemm_bt<EPI_BIAS><<<dim3(4, 128, 1), 256, 0, stream>>>(
        HID, W2t, F2, b2, 2 * D, 2 * D, 2 * D, D, 0, 0, 0);

    // out = LN(f2 + x)  -> fp32 d_out
    ln_kernel<false, true><<<BN * N, 256, 0, stream>>>(F2, X, g2, be2, (float*)d_out);
}

// Round 5
// 595.468 us; speedup vs baseline: 1.0007x; 1.0007x over previous
//
#include <hip/hip_runtime.h>

typedef unsigned short u16;
typedef __bf16 bf16x8 __attribute__((ext_vector_type(8)));
typedef float f32x4 __attribute__((ext_vector_type(4)));

// Problem constants: B=8, N=2048, DH=512
#define SEQN 2048
#define DHID 512

static __device__ __forceinline__ float bf2f(u16 u) {
    union { unsigned int i; float f; } c; c.i = ((unsigned int)u) << 16; return c.f;
}
static __device__ __forceinline__ u16 f2bf(float f) {
    union { float f; unsigned int i; } c; c.f = f;
    unsigned int x = c.i;
    return (u16)((x + 0x7fffu + ((x >> 16) & 1u)) >> 16);
}

// async global->LDS, 16B per lane, LDS dest = wave-uniform base + lane*16
static __device__ __forceinline__ void gld_lds16(const u16* g, u16* l) {
    __builtin_amdgcn_global_load_lds(
        (__attribute__((address_space(1))) void*)(g),
        (__attribute__((address_space(3))) void*)(l), 16, 0, 0);
}

// ---------------------------------------------------------------------------
// fp32 -> bf16 conversion (n multiple of 8)
// ---------------------------------------------------------------------------
__global__ __launch_bounds__(256) void cvt_kernel(const float* __restrict__ src,
                                                  u16* __restrict__ dst, int n) {
    int i = (blockIdx.x * 256 + threadIdx.x) * 8;
    if (i >= n) return;
    float4 a = *(const float4*)(src + i);
    float4 b = *(const float4*)(src + i + 4);
    union { uint4 u; u16 s[8]; } o;
    o.s[0] = f2bf(a.x); o.s[1] = f2bf(a.y); o.s[2] = f2bf(a.z); o.s[3] = f2bf(a.w);
    o.s[4] = f2bf(b.x); o.s[5] = f2bf(b.y); o.s[6] = f2bf(b.z); o.s[7] = f2bf(b.w);
    *(uint4*)(dst + i) = o.u;
}

// fp32 [K][N] -> bf16 transposed [N][K]
__global__ __launch_bounds__(256) void cvt_t_kernel(const float* __restrict__ src,
                                                    u16* __restrict__ dst, int K, int N) {
    int idx = blockIdx.x * 256 + threadIdx.x;
    if (idx >= K * N) return;
    int n = idx / K, k = idx - n * K;
    dst[idx] = f2bf(src[(size_t)k * N + n]);
}

// ---------------------------------------------------------------------------
// hop_emb row means (fp32 in): hm[j] = mean_d hop_emb[j][d]
// ---------------------------------------------------------------------------
__global__ void hmean_kernel(const float* __restrict__ hop, float* __restrict__ hm) {
    int j = blockIdx.x, t = threadIdx.x;           // 64 threads
    const float* p = hop + (size_t)j * DHID + t * 8;
    float4 a = *(const float4*)p;
    float4 b = *(const float4*)(p + 4);
    float s = a.x + a.y + a.z + a.w + b.x + b.y + b.z + b.w;
#pragma unroll
    for (int m = 1; m < 64; m <<= 1) s += __shfl_xor(s, m);
    if (t == 0) hm[j] = s * (1.0f / (float)DHID);
}

// ---------------------------------------------------------------------------
// BT MFMA GEMM: C[M,N] = A[M,K] * Bt[N,K]^T + epilogue  (A,Bt,C bf16)
// Tile 128x128x32, 256 threads (4 waves as 2x2 of 64x64), 16x16x32 MFMA.
// EPI_QKV: N=1536 concat [Q|K|Vt]; sel = gn>>9 is block-uniform.
// ---------------------------------------------------------------------------
enum { EPI_BIAS = 0, EPI_RELU = 1, EPI_PLAIN = 3, EPI_BIAS_T = 4, EPI_QKV = 5 };

template <int EPI>
__global__ __launch_bounds__(256) void gemm_bt(
    const u16* __restrict__ A, const u16* __restrict__ Bt, u16* __restrict__ C,
    const float* __restrict__ bias,
    int K, int lda, int ldb, int ldc,
    u16* __restrict__ Qo, u16* __restrict__ Ko, u16* __restrict__ Vto,
    const float* __restrict__ bq_, const float* __restrict__ bk_,
    const float* __restrict__ bv_)
{
    __shared__ u16 As[128 * 32];   // 8 KB, [row][k], row stride 64 B
    __shared__ u16 Bs[128 * 32];   // 8 KB, [n][k]

    const int tid = threadIdx.x;
    const u16* Ab = A;
    const u16* Bb = Bt;

    const int bm0 = blockIdx.y * 128, bn0 = blockIdx.x * 128;
    const int wid = tid >> 6, lane = tid & 63, quad = lane >> 4, l16 = lane & 15;
    const int wm = (wid >> 1) * 64, wn = (wid & 1) * 64;
    const int srow = lane >> 2;            // 0..15: row within 16-row chunk
    const int skof = (lane & 3) * 8;       // k element offset (8 bf16 = 16 B)

    f32x4 acc[4][4];
#pragma unroll
    for (int i = 0; i < 4; ++i)
#pragma unroll
        for (int j = 0; j < 4; ++j) acc[i][j] = (f32x4){0.f, 0.f, 0.f, 0.f};

    for (int k0 = 0; k0 < K; k0 += 32) {
#pragma unroll
        for (int it = 0; it < 2; ++it) {
            int c = wid * 2 + it;          // wave-uniform
            gld_lds16(Ab + (size_t)(bm0 + c * 16 + srow) * lda + k0 + skof,
                      &As[c * 512]);
        }
#pragma unroll
        for (int it = 0; it < 2; ++it) {
            int c = wid * 2 + it;
            gld_lds16(Bb + (size_t)(bn0 + c * 16 + srow) * ldb + k0 + skof,
                      &Bs[c * 512]);
        }
        __syncthreads();

        bf16x8 af[4], bfr[4];
#pragma unroll
        for (int i = 0; i < 4; ++i)
            af[i] = *(const bf16x8*)&As[(wm + i * 16 + l16) * 32 + quad * 8];
#pragma unroll
        for (int j = 0; j < 4; ++j)
            bfr[j] = *(const bf16x8*)&Bs[(wn + j * 16 + l16) * 32 + quad * 8];
#pragma unroll
        for (int i = 0; i < 4; ++i)
#pragma unroll
            for (int j = 0; j < 4; ++j)
                acc[i][j] = __builtin_amdgcn_mfma_f32_16x16x32_bf16(af[i], bfr[j], acc[i][j], 0, 0, 0);
        __syncthreads();
    }

    // ---- epilogue: C/D layout col=lane&15, row=quad*4+reg ----
#pragma unroll
    for (int i = 0; i < 4; ++i) {
#pragma unroll
        for (int j = 0; j < 4; ++j) {
            const int gn = bn0 + wn + j * 16 + l16;
            const int gm0 = bm0 + wm + i * 16 + quad * 4;
            if constexpr (EPI == EPI_BIAS || EPI == EPI_RELU) {
                const float b = bias[gn];
#pragma unroll
                for (int r = 0; r < 4; ++r) {
                    float v = acc[i][j][r] + b;
                    if constexpr (EPI == EPI_RELU) v = fmaxf(v, 0.f);
                    C[(size_t)(gm0 + r) * ldc + gn] = f2bf(v);
                }
            } else if constexpr (EPI == EPI_BIAS_T) {
                const float b = bias[gn];
                const int bb = gm0 >> 11, n = gm0 & 2047;
                ushort4 o;
                o.x = f2bf(acc[i][j][0] + b);
                o.y = f2bf(acc[i][j][1] + b);
                o.z = f2bf(acc[i][j][2] + b);
                o.w = f2bf(acc[i][j][3] + b);
                *(ushort4*)&C[((size_t)bb * 512 + gn) * 2048 + n] = o;
            } else if constexpr (EPI == EPI_QKV) {
                const int sel = gn >> 9;     // block-uniform (bn0 128-aligned)
                const int n = gn & 511;
                if (sel == 0) {
                    const float b = bq_[n];
#pragma unroll
                    for (int r = 0; r < 4; ++r)
                        Qo[(size_t)(gm0 + r) * DHID + n] = f2bf(acc[i][j][r] + b);
                } else if (sel == 1) {
                    const float b = bk_[n];
#pragma unroll
                    for (int r = 0; r < 4; ++r)
                        Ko[(size_t)(gm0 + r) * DHID + n] = f2bf(acc[i][j][r] + b);
                } else {
                    const float b = bv_[n];
                    const int bb = gm0 >> 11, nn2 = gm0 & 2047;
                    ushort4 o;
                    o.x = f2bf(acc[i][j][0] + b);
                    o.y = f2bf(acc[i][j][1] + b);
                    o.z = f2bf(acc[i][j][2] + b);
                    o.w = f2bf(acc[i][j][3] + b);
                    *(ushort4*)&Vto[((size_t)bb * 512 + n) * 2048 + nn2] = o;
                }
            } else {
#pragma unroll
                for (int r = 0; r < 4; ++r)
                    C[(size_t)(gm0 + r) * ldc + gn] = f2bf(acc[i][j][r]);
            }
        }
    }
}

// ---------------------------------------------------------------------------
// Fused attention, kv-split: block = (batch bx, 64 Q-rows by, kv-half bz).
// Writes UNNORMALIZED O-partial (bf16) and row-sum partial (fp32).
// LDS: Ks 32KB [ds16][kv32][d32] | Vs 32KB [d512][kv32]; P aliases Ks region.
// ---------------------------------------------------------------------------
__global__ __launch_bounds__(256, 1) void attn_kernel(
    const u16* __restrict__ Q, const u16* __restrict__ K, const u16* __restrict__ Vt,
    const float* __restrict__ adj, const float* __restrict__ hm,
    u16* __restrict__ Opart, float* __restrict__ Lpart)
{
    extern __shared__ u16 lds[];                 // 65536 B
    u16* Ks = lds;                               // 16384 u16
    u16* Vs = lds + 16384;                       // 16384 u16

    const int tid = threadIdx.x, wid = tid >> 6, lane = tid & 63;
    const int quad = lane >> 4, l16 = lane & 15;
    const int b = blockIdx.x;                    // batch -> XCD affinity
    const int q0w = blockIdx.y * 64 + wid * 16;  // wave's 16 Q-rows
    const int z = blockIdx.z;                    // kv half
    const int srow = lane >> 2, sko = (lane & 3) * 8;

    const u16* Qg = Q + (size_t)b * SEQN * DHID;
    const u16* Kg = K + (size_t)b * SEQN * DHID;
    const u16* Vg = Vt + (size_t)b * DHID * SEQN;
    const float* adjg = adj + (size_t)b * SEQN * SEQN;
    u16* Og = Opart + ((size_t)z * 8 + b) * SEQN * DHID;
    u16* Plds = lds + wid * 640;                 // 16 rows x 40 u16, in Ks region

    const float scale = 0.044194173824159216f;   // 1/sqrt(512)

    // Q fragments (A-layout): lane holds Q[q0w+l16][ds*32+quad*8+j]
    bf16x8 qf[16];
#pragma unroll
    for (int ds = 0; ds < 16; ++ds)
        qf[ds] = *(const bf16x8*)(Qg + (size_t)(q0w + l16) * DHID + ds * 32 + quad * 8);

    f32x4 oacc[32];
#pragma unroll
    for (int dt = 0; dt < 32; ++dt) oacc[dt] = (f32x4){0.f, 0.f, 0.f, 0.f};
    float lsum[4] = {0.f, 0.f, 0.f, 0.f};

    for (int kt = 0; kt < 32; ++kt) {
        const int kv0 = z * 1024 + kt * 32;

        // ---- stage Ks [ds][kv 16c..16c+16)[d32] ----
#pragma unroll
        for (int i = 0; i < 8; ++i) {
            int id = wid * 8 + i;                // wave-uniform
            int ds = id >> 1, c = id & 1;
            gld_lds16(Kg + (size_t)(kv0 + c * 16 + srow) * DHID + ds * 32 + sko,
                      &Ks[ds * 1024 + c * 512]);
        }
        __syncthreads();                         // Ks ready

        // ---- stage Vs async (consumed in PV phase) ----
#pragma unroll
        for (int i = 0; i < 8; ++i) {
            int id = wid * 8 + i;                // d-rows id*16..id*16+16
            gld_lds16(Vg + (size_t)(id * 16 + srow) * SEQN + kv0 + sko,
                      &Vs[id * 512]);
        }

        // ---- early scalar loads ----
        float hv0 = hm[kv0 + l16] * scale;
        float hv1 = hm[kv0 + 16 + l16] * scale;
        float av[8];
        const float* arow = adjg + (size_t)(q0w + quad * 4) * SEQN + kv0;
#pragma unroll
        for (int r = 0; r < 4; ++r) {
            av[r]     = arow[(size_t)r * SEQN + l16];
            av[4 + r] = arow[(size_t)r * SEQN + 16 + l16];
        }

        // ---- QK^T: S 16x32, 4 independent chains ----
        f32x4 s0a = {0.f,0.f,0.f,0.f}, s0b = {0.f,0.f,0.f,0.f};
        f32x4 s1a = {0.f,0.f,0.f,0.f}, s1b = {0.f,0.f,0.f,0.f};
#pragma unroll
        for (int ds = 0; ds < 16; ds += 2) {
            bf16x8 k00 = *(const bf16x8*)&Ks[ds * 1024 + l16 * 32 + quad * 8];
            bf16x8 k01 = *(const bf16x8*)&Ks[ds * 1024 + 512 + l16 * 32 + quad * 8];
            s0a = __builtin_amdgcn_mfma_f32_16x16x32_bf16(qf[ds], k00, s0a, 0, 0, 0);
            s1a = __builtin_amdgcn_mfma_f32_16x16x32_bf16(qf[ds], k01, s1a, 0, 0, 0);
            bf16x8 k10 = *(const bf16x8*)&Ks[(ds + 1) * 1024 + l16 * 32 + quad * 8];
            bf16x8 k11 = *(const bf16x8*)&Ks[(ds + 1) * 1024 + 512 + l16 * 32 + quad * 8];
            s0b = __builtin_amdgcn_mfma_f32_16x16x32_bf16(qf[ds + 1], k10, s0b, 0, 0, 0);
            s1b = __builtin_amdgcn_mfma_f32_16x16x32_bf16(qf[ds + 1], k11, s1b, 0, 0, 0);
        }
        f32x4 s0 = s0a + s0b, s1 = s1a + s1b;
        __syncthreads();                         // Ks reads done; Vs drained

        // ---- P = exp(s'), row-sum accumulate, LDS transpose ----
#pragma unroll
        for (int r = 0; r < 4; ++r) {
            float p0 = __expf(s0[r] * av[r] * hv0);
            float p1 = __expf(s1[r] * av[4 + r] * hv1);
            lsum[r] += p0 + p1;
            Plds[(quad * 4 + r) * 40 + l16] = f2bf(p0);
            Plds[(quad * 4 + r) * 40 + 16 + l16] = f2bf(p1);
        }
        asm volatile("s_waitcnt lgkmcnt(0)" ::: "memory");

        // ---- PV: O[16x512] += P[16x32] @ V[32x512] ----
        bf16x8 pf = *(const bf16x8*)&Plds[l16 * 40 + quad * 8];
#pragma unroll
        for (int dt = 0; dt < 32; ++dt) {
            bf16x8 vf = *(const bf16x8*)&Vs[(dt * 16 + l16) * 32 + quad * 8];
            oacc[dt] = __builtin_amdgcn_mfma_f32_16x16x32_bf16(pf, vf, oacc[dt], 0, 0, 0);
        }
        __syncthreads();                         // done reading P/Vs
    }

    // ---- store partial row sums + unnormalized O ----
#pragma unroll
    for (int r = 0; r < 4; ++r) {
#pragma unroll
        for (int m = 1; m < 16; m <<= 1) lsum[r] += __shfl_xor(lsum[r], m);
        if (l16 == 0)
            Lpart[(size_t)z * 16384 + b * 2048 + q0w + quad * 4 + r] = lsum[r];
    }
#pragma unroll
    for (int dt = 0; dt < 32; ++dt) {
#pragma unroll
        for (int r = 0; r < 4; ++r) {
            Og[(size_t)(q0w + quad * 4 + r) * DHID + dt * 16 + l16] =
                f2bf(oacc[dt][r]);
        }
    }
}

// ---------------------------------------------------------------------------
// LN1 + combine: x = LN((O1+O2)/(l1+l2) + H) * g + be   (out bf16)
// ---------------------------------------------------------------------------
__global__ __launch_bounds__(256) void ln_comb_kernel(
    const u16* __restrict__ O1, const u16* __restrict__ O2,
    const float* __restrict__ L1, const float* __restrict__ L2,
    const float* __restrict__ Hf,
    const float* __restrict__ g, const float* __restrict__ be,
    u16* __restrict__ out)
{
    size_t row = blockIdx.x;
    int t = threadIdx.x, wid = t >> 6, lane = t & 63;
    float sc = 1.f / (L1[row] + L2[row]);

    unsigned int a1 = *(const unsigned int*)(O1 + row * (size_t)DHID + t * 2);
    unsigned int a2 = *(const unsigned int*)(O2 + row * (size_t)DHID + t * 2);
    float2 h = *(const float2*)(Hf + row * (size_t)DHID + t * 2);
    float x0 = (bf2f((u16)(a1 & 0xffff)) + bf2f((u16)(a2 & 0xffff))) * sc + h.x;
    float x1 = (bf2f((u16)(a1 >> 16)) + bf2f((u16)(a2 >> 16))) * sc + h.y;

    float s = x0 + x1, sq = x0 * x0 + x1 * x1;
#pragma unroll
    for (int m = 1; m < 64; m <<= 1) { s += __shfl_xor(s, m); sq += __shfl_xor(sq, m); }
    __shared__ float rs[4], rq[4];
    if (lane == 0) { rs[wid] = s; rq[wid] = sq; }
    __syncthreads();
    s = rs[0] + rs[1] + rs[2] + rs[3];
    sq = rq[0] + rq[1] + rq[2] + rq[3];
    float mean = s * (1.f / (float)DHID);
    float var = sq * (1.f / (float)DHID) - mean * mean;
    float rstd = rsqrtf(var + 1e-5f);

    float2 vg = *(const float2*)(g + t * 2);
    float2 vbe = *(const float2*)(be + t * 2);
    float y0 = (x0 - mean) * rstd * vg.x + vbe.x;
    float y1 = (x1 - mean) * rstd * vg.y + vbe.y;
    unsigned int o = (unsigned int)f2bf(y0) | ((unsigned int)f2bf(y1) << 16);
    *(unsigned int*)(out + row * (size_t)DHID + t * 2) = o;
}

// ---------------------------------------------------------------------------
// LayerNorm: out = LN(a + b) * g + be   (a bf16, b bf16, out fp32)
// ---------------------------------------------------------------------------
__global__ __launch_bounds__(256) void ln_kernel_f32out(
    const u16* __restrict__ a, const u16* __restrict__ bp,
    const float* __restrict__ g, const float* __restrict__ be,
    float* __restrict__ out)
{
    size_t row = blockIdx.x;
    int t = threadIdx.x, wid = t >> 6, lane = t & 63;
    unsigned int va = *(const unsigned int*)(a + row * (size_t)DHID + t * 2);
    unsigned int vb = *(const unsigned int*)(bp + row * (size_t)DHID + t * 2);
    float x0 = bf2f((u16)(va & 0xffff)) + bf2f((u16)(vb & 0xffff));
    float x1 = bf2f((u16)(va >> 16)) + bf2f((u16)(vb >> 16));
    float s = x0 + x1, sq = x0 * x0 + x1 * x1;
#pragma unroll
    for (int m = 1; m < 64; m <<= 1) { s += __shfl_xor(s, m); sq += __shfl_xor(sq, m); }
    __shared__ float rs[4], rq[4];
    if (lane == 0) { rs[wid] = s; rq[wid] = sq; }
    __syncthreads();
    s = rs[0] + rs[1] + rs[2] + rs[3];
    sq = rq[0] + rq[1] + rq[2] + rq[3];
    float mean = s * (1.f / (float)DHID);
    float var = sq * (1.f / (float)DHID) - mean * mean;
    float rstd = rsqrtf(var + 1e-5f);
    float2 vg = *(const float2*)(g + t * 2);
    float2 vbe = *(const float2*)(be + t * 2);
    float y0 = (x0 - mean) * rstd * vg.x + vbe.x;
    float y1 = (x1 - mean) * rstd * vg.y + vbe.y;
    *(float2*)(out + row * (size_t)DHID + t * 2) = make_float2(y0, y1);
}

// ---------------------------------------------------------------------------
extern "C" void kernel_launch(void* const* d_in, const int* in_sizes, int n_in,
                              void* d_out, int out_size, void* d_ws, size_t ws_size,
                              hipStream_t stream) {
    const float* H   = (const float*)d_in[0];
    const float* adj = (const float*)d_in[1];
    const float* hop = (const float*)d_in[2];
    const float* Wq  = (const float*)d_in[3];
    const float* bq  = (const float*)d_in[4];
    const float* Wk  = (const float*)d_in[5];
    const float* bk  = (const float*)d_in[6];
    const float* Wv  = (const float*)d_in[7];
    const float* bv  = (const float*)d_in[8];
    const float* W1  = (const float*)d_in[9];
    const float* b1  = (const float*)d_in[10];
    const float* W2  = (const float*)d_in[11];
    const float* b2  = (const float*)d_in[12];
    const float* g1  = (const float*)d_in[13];
    const float* be1 = (const float*)d_in[14];
    const float* g2  = (const float*)d_in[15];
    const float* be2 = (const float*)d_in[16];

    const size_t MiB = 1ull << 20;
    char* w = (char*)d_ws;
    float* hm   = (float*)w;                      // 8 KB
    float* Lp   = (float*)(w + 256 * 1024);       // 2 x 16384 fp32 = 128 KB
    u16* Hb    = (u16*)(w + 1 * MiB);             // 16 MiB
    u16* Wqkvt = (u16*)(w + 17 * MiB);            // 1.5 MiB [Wq^T|Wk^T|Wv^T]
    u16* W1t   = (u16*)(w + 18 * MiB + 512 * 1024); // 1 MiB
    u16* W2t   = (u16*)(w + 19 * MiB + 512 * 1024); // 1 MiB
    u16* Q     = (u16*)(w + 21 * MiB);            // 16 MiB
    u16* Kb    = (u16*)(w + 37 * MiB);            // 16 MiB
    u16* Vt    = (u16*)(w + 53 * MiB);            // 16 MiB  [b][512][2048]
    u16* O1    = (u16*)(w + 69 * MiB);            // 16 MiB  (unnormalized)
    u16* O2    = (u16*)(w + 85 * MiB);            // 16 MiB
    u16* HID   = (u16*)(w + 101 * MiB);           // 32 MiB -> total 133 MiB
    // aliases (lifetimes disjoint):
    u16* X   = Kb;   // LN1 output (K dead after attention)
    u16* F2  = Vt;   // ffn2 output (V dead after attention)

    const int BN = 8, N = SEQN, D = DHID;

    // fp32 -> bf16 conversions (weights transposed, QKV concatenated)
    cvt_kernel<<<(BN * N * D) / (8 * 256), 256, 0, stream>>>(H, Hb, BN * N * D);
    cvt_t_kernel<<<(D * D + 255) / 256, 256, 0, stream>>>(Wq, Wqkvt, D, D);
    cvt_t_kernel<<<(D * D + 255) / 256, 256, 0, stream>>>(Wk, Wqkvt + D * D, D, D);
    cvt_t_kernel<<<(D * D + 255) / 256, 256, 0, stream>>>(Wv, Wqkvt + 2 * D * D, D, D);
    cvt_t_kernel<<<(D * 2 * D + 255) / 256, 256, 0, stream>>>(W1, W1t, D, 2 * D);
    cvt_t_kernel<<<(2 * D * D + 255) / 256, 256, 0, stream>>>(W2, W2t, 2 * D, D);

    hmean_kernel<<<N, 64, 0, stream>>>(hop, hm);

    // fused QKV: C[16384,1536] over [Q|K|Vt] outputs
    gemm_bt<EPI_QKV><<<dim3(12, 128, 1), 256, 0, stream>>>(
        Hb, Wqkvt, nullptr, nullptr, D, D, D, 0, Q, Kb, Vt, bq, bk, bv);

    // fused attention, kv-split x2: 512 blocks -> 2 blocks/CU
    attn_kernel<<<dim3(8, 32, 2), 256, 65536, stream>>>(
        Q, Kb, Vt, adj, hm, O1, Lp);

    // x = LN((O1+O2)/(l1+l2) + H)
    ln_comb_kernel<<<BN * N, 256, 0, stream>>>(
        O1, O2, Lp, Lp + 16384, H, g1, be1, X);

    // hid = relu(x @ W1 + b1)
    gemm_bt<EPI_RELU><<<dim3(8, 128, 1), 256, 0, stream>>>(
        X, W1t, HID, b1, D, D, D, 2 * D, nullptr, nullptr, nullptr, nullptr, nullptr, nullptr);

    // f2 = hid @ W2 + b2
    gemm_bt<EPI_BIAS><<<dim3(4, 128, 1), 256, 0, stream>>>(
        HID, W2t, F2, b2, 2 * D, 2 * D, 2 * D, D, nullptr, nullptr, nullptr, nullptr, nullptr, nullptr);

    // out = LN(f2 + x)  -> fp32 d_out
    ln_kernel_f32out<<<BN * N, 256, 0, stream>>>(F2, X, g2, be2, (float*)d_out);
}

// Round 6
// 559.401 us; speedup vs baseline: 1.0652x; 1.0645x over previous
//
#include <hip/hip_runtime.h>

typedef unsigned short u16;
typedef __bf16 bf16x8 __attribute__((ext_vector_type(8)));
typedef float f32x4 __attribute__((ext_vector_type(4)));

// Problem constants: B=8, N=2048, DH=512
#define SEQN 2048
#define DHID 512

static __device__ __forceinline__ float bf2f(u16 u) {
    union { unsigned int i; float f; } c; c.i = ((unsigned int)u) << 16; return c.f;
}
static __device__ __forceinline__ u16 f2bf(float f) {
    union { float f; unsigned int i; } c; c.f = f;
    unsigned int x = c.i;
    return (u16)((x + 0x7fffu + ((x >> 16) & 1u)) >> 16);
}

// async global->LDS, 16B per lane, LDS dest = wave-uniform base + lane*16
static __device__ __forceinline__ void gld_lds16(const u16* g, u16* l) {
    __builtin_amdgcn_global_load_lds(
        (__attribute__((address_space(1))) void*)(g),
        (__attribute__((address_space(3))) void*)(l), 16, 0, 0);
}

// ---------------------------------------------------------------------------
// fp32 -> bf16 conversion (n multiple of 8)
// ---------------------------------------------------------------------------
__global__ __launch_bounds__(256) void cvt_kernel(const float* __restrict__ src,
                                                  u16* __restrict__ dst, int n) {
    int i = (blockIdx.x * 256 + threadIdx.x) * 8;
    if (i >= n) return;
    float4 a = *(const float4*)(src + i);
    float4 b = *(const float4*)(src + i + 4);
    union { uint4 u; u16 s[8]; } o;
    o.s[0] = f2bf(a.x); o.s[1] = f2bf(a.y); o.s[2] = f2bf(a.z); o.s[3] = f2bf(a.w);
    o.s[4] = f2bf(b.x); o.s[5] = f2bf(b.y); o.s[6] = f2bf(b.z); o.s[7] = f2bf(b.w);
    *(uint4*)(dst + i) = o.u;
}

// fp32 [K][N] -> bf16 transposed [N][K]
__global__ __launch_bounds__(256) void cvt_t_kernel(const float* __restrict__ src,
                                                    u16* __restrict__ dst, int K, int N) {
    int idx = blockIdx.x * 256 + threadIdx.x;
    if (idx >= K * N) return;
    int n = idx / K, k = idx - n * K;
    dst[idx] = f2bf(src[(size_t)k * N + n]);
}

// ---------------------------------------------------------------------------
// hop_emb row means (fp32 in): hm[j] = mean_d hop_emb[j][d]
// ---------------------------------------------------------------------------
__global__ void hmean_kernel(const float* __restrict__ hop, float* __restrict__ hm) {
    int j = blockIdx.x, t = threadIdx.x;           // 64 threads
    const float* p = hop + (size_t)j * DHID + t * 8;
    float4 a = *(const float4*)p;
    float4 b = *(const float4*)(p + 4);
    float s = a.x + a.y + a.z + a.w + b.x + b.y + b.z + b.w;
#pragma unroll
    for (int m = 1; m < 64; m <<= 1) s += __shfl_xor(s, m);
    if (t == 0) hm[j] = s * (1.0f / (float)DHID);
}

// ---------------------------------------------------------------------------
// BT MFMA GEMM: C[M,N] = A[M,K] * Bt[N,K]^T + epilogue  (A,Bt,C bf16)
// Tile 128x128x32, 256 threads (4 waves as 2x2 of 64x64), 16x16x32 MFMA.
// EPI_QKV: N=1536 concat [Q|K|Vt]; sel = gn>>9 is block-uniform.
// ---------------------------------------------------------------------------
enum { EPI_BIAS = 0, EPI_RELU = 1, EPI_PLAIN = 3, EPI_BIAS_T = 4, EPI_QKV = 5 };

template <int EPI>
__global__ __launch_bounds__(256) void gemm_bt(
    const u16* __restrict__ A, const u16* __restrict__ Bt, u16* __restrict__ C,
    const float* __restrict__ bias,
    int K, int lda, int ldb, int ldc,
    u16* __restrict__ Qo, u16* __restrict__ Ko, u16* __restrict__ Vto,
    const float* __restrict__ bq_, const float* __restrict__ bk_,
    const float* __restrict__ bv_)
{
    __shared__ u16 As[128 * 32];   // 8 KB, [row][k], row stride 64 B
    __shared__ u16 Bs[128 * 32];   // 8 KB, [n][k]

    const int tid = threadIdx.x;
    const u16* Ab = A;
    const u16* Bb = Bt;

    const int bm0 = blockIdx.y * 128, bn0 = blockIdx.x * 128;
    const int wid = tid >> 6, lane = tid & 63, quad = lane >> 4, l16 = lane & 15;
    const int wm = (wid >> 1) * 64, wn = (wid & 1) * 64;
    const int srow = lane >> 2;            // 0..15: row within 16-row chunk
    const int skof = (lane & 3) * 8;       // k element offset (8 bf16 = 16 B)

    f32x4 acc[4][4];
#pragma unroll
    for (int i = 0; i < 4; ++i)
#pragma unroll
        for (int j = 0; j < 4; ++j) acc[i][j] = (f32x4){0.f, 0.f, 0.f, 0.f};

    for (int k0 = 0; k0 < K; k0 += 32) {
#pragma unroll
        for (int it = 0; it < 2; ++it) {
            int c = wid * 2 + it;          // wave-uniform
            gld_lds16(Ab + (size_t)(bm0 + c * 16 + srow) * lda + k0 + skof,
                      &As[c * 512]);
        }
#pragma unroll
        for (int it = 0; it < 2; ++it) {
            int c = wid * 2 + it;
            gld_lds16(Bb + (size_t)(bn0 + c * 16 + srow) * ldb + k0 + skof,
                      &Bs[c * 512]);
        }
        __syncthreads();

        bf16x8 af[4], bfr[4];
#pragma unroll
        for (int i = 0; i < 4; ++i)
            af[i] = *(const bf16x8*)&As[(wm + i * 16 + l16) * 32 + quad * 8];
#pragma unroll
        for (int j = 0; j < 4; ++j)
            bfr[j] = *(const bf16x8*)&Bs[(wn + j * 16 + l16) * 32 + quad * 8];
#pragma unroll
        for (int i = 0; i < 4; ++i)
#pragma unroll
            for (int j = 0; j < 4; ++j)
                acc[i][j] = __builtin_amdgcn_mfma_f32_16x16x32_bf16(af[i], bfr[j], acc[i][j], 0, 0, 0);
        __syncthreads();
    }

    // ---- epilogue: C/D layout col=lane&15, row=quad*4+reg ----
#pragma unroll
    for (int i = 0; i < 4; ++i) {
#pragma unroll
        for (int j = 0; j < 4; ++j) {
            const int gn = bn0 + wn + j * 16 + l16;
            const int gm0 = bm0 + wm + i * 16 + quad * 4;
            if constexpr (EPI == EPI_BIAS || EPI == EPI_RELU) {
                const float b = bias[gn];
#pragma unroll
                for (int r = 0; r < 4; ++r) {
                    float v = acc[i][j][r] + b;
                    if constexpr (EPI == EPI_RELU) v = fmaxf(v, 0.f);
                    C[(size_t)(gm0 + r) * ldc + gn] = f2bf(v);
                }
            } else if constexpr (EPI == EPI_BIAS_T) {
                const float b = bias[gn];
                const int bb = gm0 >> 11, n = gm0 & 2047;
                ushort4 o;
                o.x = f2bf(acc[i][j][0] + b);
                o.y = f2bf(acc[i][j][1] + b);
                o.z = f2bf(acc[i][j][2] + b);
                o.w = f2bf(acc[i][j][3] + b);
                *(ushort4*)&C[((size_t)bb * 512 + gn) * 2048 + n] = o;
            } else if constexpr (EPI == EPI_QKV) {
                const int sel = gn >> 9;     // block-uniform (bn0 128-aligned)
                const int n = gn & 511;
                if (sel == 0) {
                    const float b = bq_[n];
#pragma unroll
                    for (int r = 0; r < 4; ++r)
                        Qo[(size_t)(gm0 + r) * DHID + n] = f2bf(acc[i][j][r] + b);
                } else if (sel == 1) {
                    const float b = bk_[n];
#pragma unroll
                    for (int r = 0; r < 4; ++r)
                        Ko[(size_t)(gm0 + r) * DHID + n] = f2bf(acc[i][j][r] + b);
                } else {
                    const float b = bv_[n];
                    const int bb = gm0 >> 11, nn2 = gm0 & 2047;
                    ushort4 o;
                    o.x = f2bf(acc[i][j][0] + b);
                    o.y = f2bf(acc[i][j][1] + b);
                    o.z = f2bf(acc[i][j][2] + b);
                    o.w = f2bf(acc[i][j][3] + b);
                    *(ushort4*)&Vto[((size_t)bb * 512 + n) * 2048 + nn2] = o;
                }
            } else {
#pragma unroll
                for (int r = 0; r < 4; ++r)
                    C[(size_t)(gm0 + r) * ldc + gn] = f2bf(acc[i][j][r]);
            }
        }
    }
}

// ---------------------------------------------------------------------------
// Fused attention v3: block = (batch bx, 32 Q-rows by). 4 waves:
// wave w -> rows 16*(w>>1), d-half (w&1)*256. QK^T computed per row-pair
// (redundant across d-half waves, keeps P wave-private); PV only 16 dt tiles
// -> oacc = 64 regs -> total regs < 256 -> 2 waves/SIMD -> 2 blocks/CU.
// LDS: Ks 32KB [ds16][kv32][d32] | Vs 32KB [d512][kv32]; P aliases Ks region.
// ---------------------------------------------------------------------------
__global__ __launch_bounds__(256, 2) void attn_kernel(
    const u16* __restrict__ Q, const u16* __restrict__ K, const u16* __restrict__ Vt,
    const float* __restrict__ adj, const float* __restrict__ hm,
    u16* __restrict__ AO)
{
    extern __shared__ u16 lds[];                 // 65536 B
    u16* Ks = lds;                               // 16384 u16
    u16* Vs = lds + 16384;                       // 16384 u16

    const int tid = threadIdx.x, wid = tid >> 6, lane = tid & 63;
    const int quad = lane >> 4, l16 = lane & 15;
    const int b = blockIdx.x;                    // batch -> XCD affinity
    const int q0 = blockIdx.y * 32 + (wid >> 1) * 16;  // wave's 16 Q-rows
    const int D0 = (wid & 1) * 256;              // wave's d-half for PV
    const int srow = lane >> 2, sko = (lane & 3) * 8;

    const u16* Qg = Q + (size_t)b * SEQN * DHID;
    const u16* Kg = K + (size_t)b * SEQN * DHID;
    const u16* Vg = Vt + (size_t)b * DHID * SEQN;
    const float* adjg = adj + (size_t)b * SEQN * SEQN;
    u16* AOg = AO + (size_t)b * SEQN * DHID;
    u16* Plds = lds + wid * 640;                 // 16 rows x 40 u16, in Ks region

    const float scale = 0.044194173824159216f;   // 1/sqrt(512)

    // Q fragments (A-layout): lane holds Q[q0+l16][ds*32+quad*8+j]
    bf16x8 qf[16];
#pragma unroll
    for (int ds = 0; ds < 16; ++ds)
        qf[ds] = *(const bf16x8*)(Qg + (size_t)(q0 + l16) * DHID + ds * 32 + quad * 8);

    f32x4 oacc[16];
#pragma unroll
    for (int dt = 0; dt < 16; ++dt) oacc[dt] = (f32x4){0.f, 0.f, 0.f, 0.f};
    float lsum[4] = {0.f, 0.f, 0.f, 0.f};

    for (int kt = 0; kt < 64; ++kt) {
        const int kv0 = kt * 32;

        // ---- stage Ks [ds][kv 16c..16c+16)[d32] ----
#pragma unroll
        for (int i = 0; i < 8; ++i) {
            int id = wid * 8 + i;                // wave-uniform
            int ds = id >> 1, c = id & 1;
            gld_lds16(Kg + (size_t)(kv0 + c * 16 + srow) * DHID + ds * 32 + sko,
                      &Ks[ds * 1024 + c * 512]);
        }
        __syncthreads();                         // Ks ready; prev-iter P reads done

        // ---- stage Vs async (consumed in PV phase) ----
#pragma unroll
        for (int i = 0; i < 8; ++i) {
            int id = wid * 8 + i;                // d-rows id*16..id*16+16
            gld_lds16(Vg + (size_t)(id * 16 + srow) * SEQN + kv0 + sko,
                      &Vs[id * 512]);
        }

        // ---- early scalar loads ----
        float hv0 = hm[kv0 + l16] * scale;
        float hv1 = hm[kv0 + 16 + l16] * scale;
        float av[8];
        const float* arow = adjg + (size_t)(q0 + quad * 4) * SEQN + kv0;
#pragma unroll
        for (int r = 0; r < 4; ++r) {
            av[r]     = arow[(size_t)r * SEQN + l16];
            av[4 + r] = arow[(size_t)r * SEQN + 16 + l16];
        }

        // ---- QK^T: S 16x32, 4 independent chains ----
        f32x4 s0a = {0.f,0.f,0.f,0.f}, s0b = {0.f,0.f,0.f,0.f};
        f32x4 s1a = {0.f,0.f,0.f,0.f}, s1b = {0.f,0.f,0.f,0.f};
#pragma unroll
        for (int ds = 0; ds < 16; ds += 2) {
            bf16x8 k00 = *(const bf16x8*)&Ks[ds * 1024 + l16 * 32 + quad * 8];
            bf16x8 k01 = *(const bf16x8*)&Ks[ds * 1024 + 512 + l16 * 32 + quad * 8];
            s0a = __builtin_amdgcn_mfma_f32_16x16x32_bf16(qf[ds], k00, s0a, 0, 0, 0);
            s1a = __builtin_amdgcn_mfma_f32_16x16x32_bf16(qf[ds], k01, s1a, 0, 0, 0);
            bf16x8 k10 = *(const bf16x8*)&Ks[(ds + 1) * 1024 + l16 * 32 + quad * 8];
            bf16x8 k11 = *(const bf16x8*)&Ks[(ds + 1) * 1024 + 512 + l16 * 32 + quad * 8];
            s0b = __builtin_amdgcn_mfma_f32_16x16x32_bf16(qf[ds + 1], k10, s0b, 0, 0, 0);
            s1b = __builtin_amdgcn_mfma_f32_16x16x32_bf16(qf[ds + 1], k11, s1b, 0, 0, 0);
        }
        f32x4 s0 = s0a + s0b, s1 = s1a + s1b;
        __syncthreads();                         // Ks reads done (all waves); Vs drained

        // ---- P = exp(s'), row-sum accumulate, LDS transpose (wave-private) ----
#pragma unroll
        for (int r = 0; r < 4; ++r) {
            float p0 = __expf(s0[r] * av[r] * hv0);
            float p1 = __expf(s1[r] * av[4 + r] * hv1);
            lsum[r] += p0 + p1;
            Plds[(quad * 4 + r) * 40 + l16] = f2bf(p0);
            Plds[(quad * 4 + r) * 40 + 16 + l16] = f2bf(p1);
        }
        asm volatile("s_waitcnt lgkmcnt(0)" ::: "memory");

        // ---- PV: O[16 x 256] += P[16x32] @ V[32 x d-half] ----
        bf16x8 pf = *(const bf16x8*)&Plds[l16 * 40 + quad * 8];
#pragma unroll
        for (int dt = 0; dt < 16; ++dt) {
            bf16x8 vf = *(const bf16x8*)&Vs[(D0 + dt * 16 + l16) * 32 + quad * 8];
            oacc[dt] = __builtin_amdgcn_mfma_f32_16x16x32_bf16(pf, vf, oacc[dt], 0, 0, 0);
        }
        __syncthreads();                         // done reading P/Vs before restage
    }

    // ---- finalize: reduce row sums over l16 group, normalize, store ----
#pragma unroll
    for (int r = 0; r < 4; ++r) {
#pragma unroll
        for (int m = 1; m < 16; m <<= 1) lsum[r] += __shfl_xor(lsum[r], m);
        lsum[r] = 1.f / lsum[r];
    }
#pragma unroll
    for (int dt = 0; dt < 16; ++dt) {
#pragma unroll
        for (int r = 0; r < 4; ++r) {
            AOg[(size_t)(q0 + quad * 4 + r) * DHID + D0 + dt * 16 + l16] =
                f2bf(oacc[dt][r] * lsum[r]);
        }
    }
}

// ---------------------------------------------------------------------------
// LN1: x = LN(a + Hf) * g + be   (a bf16, Hf fp32, out bf16)
// ---------------------------------------------------------------------------
__global__ __launch_bounds__(256) void ln_hf32_kernel(
    const u16* __restrict__ a, const float* __restrict__ Hf,
    const float* __restrict__ g, const float* __restrict__ be,
    u16* __restrict__ out)
{
    size_t row = blockIdx.x;
    int t = threadIdx.x, wid = t >> 6, lane = t & 63;
    unsigned int va = *(const unsigned int*)(a + row * (size_t)DHID + t * 2);
    float2 h = *(const float2*)(Hf + row * (size_t)DHID + t * 2);
    float x0 = bf2f((u16)(va & 0xffff)) + h.x;
    float x1 = bf2f((u16)(va >> 16)) + h.y;
    float s = x0 + x1, sq = x0 * x0 + x1 * x1;
#pragma unroll
    for (int m = 1; m < 64; m <<= 1) { s += __shfl_xor(s, m); sq += __shfl_xor(sq, m); }
    __shared__ float rs[4], rq[4];
    if (lane == 0) { rs[wid] = s; rq[wid] = sq; }
    __syncthreads();
    s = rs[0] + rs[1] + rs[2] + rs[3];
    sq = rq[0] + rq[1] + rq[2] + rq[3];
    float mean = s * (1.f / (float)DHID);
    float var = sq * (1.f / (float)DHID) - mean * mean;
    float rstd = rsqrtf(var + 1e-5f);
    float2 vg = *(const float2*)(g + t * 2);
    float2 vbe = *(const float2*)(be + t * 2);
    float y0 = (x0 - mean) * rstd * vg.x + vbe.x;
    float y1 = (x1 - mean) * rstd * vg.y + vbe.y;
    unsigned int o = (unsigned int)f2bf(y0) | ((unsigned int)f2bf(y1) << 16);
    *(unsigned int*)(out + row * (size_t)DHID + t * 2) = o;
}

// ---------------------------------------------------------------------------
// LN2: out = LN(a + b) * g + be   (a,b bf16, out fp32)
// ---------------------------------------------------------------------------
__global__ __launch_bounds__(256) void ln_kernel_f32out(
    const u16* __restrict__ a, const u16* __restrict__ bp,
    const float* __restrict__ g, const float* __restrict__ be,
    float* __restrict__ out)
{
    size_t row = blockIdx.x;
    int t = threadIdx.x, wid = t >> 6, lane = t & 63;
    unsigned int va = *(const unsigned int*)(a + row * (size_t)DHID + t * 2);
    unsigned int vb = *(const unsigned int*)(bp + row * (size_t)DHID + t * 2);
    float x0 = bf2f((u16)(va & 0xffff)) + bf2f((u16)(vb & 0xffff));
    float x1 = bf2f((u16)(va >> 16)) + bf2f((u16)(vb >> 16));
    float s = x0 + x1, sq = x0 * x0 + x1 * x1;
#pragma unroll
    for (int m = 1; m < 64; m <<= 1) { s += __shfl_xor(s, m); sq += __shfl_xor(sq, m); }
    __shared__ float rs[4], rq[4];
    if (lane == 0) { rs[wid] = s; rq[wid] = sq; }
    __syncthreads();
    s = rs[0] + rs[1] + rs[2] + rs[3];
    sq = rq[0] + rq[1] + rq[2] + rq[3];
    float mean = s * (1.f / (float)DHID);
    float var = sq * (1.f / (float)DHID) - mean * mean;
    float rstd = rsqrtf(var + 1e-5f);
    float2 vg = *(const float2*)(g + t * 2);
    float2 vbe = *(const float2*)(be + t * 2);
    float y0 = (x0 - mean) * rstd * vg.x + vbe.x;
    float y1 = (x1 - mean) * rstd * vg.y + vbe.y;
    *(float2*)(out + row * (size_t)DHID + t * 2) = make_float2(y0, y1);
}

// ---------------------------------------------------------------------------
extern "C" void kernel_launch(void* const* d_in, const int* in_sizes, int n_in,
                              void* d_out, int out_size, void* d_ws, size_t ws_size,
                              hipStream_t stream) {
    const float* H   = (const float*)d_in[0];
    const float* adj = (const float*)d_in[1];
    const float* hop = (const float*)d_in[2];
    const float* Wq  = (const float*)d_in[3];
    const float* bq  = (const float*)d_in[4];
    const float* Wk  = (const float*)d_in[5];
    const float* bk  = (const float*)d_in[6];
    const float* Wv  = (const float*)d_in[7];
    const float* bv  = (const float*)d_in[8];
    const float* W1  = (const float*)d_in[9];
    const float* b1  = (const float*)d_in[10];
    const float* W2  = (const float*)d_in[11];
    const float* b2  = (const float*)d_in[12];
    const float* g1  = (const float*)d_in[13];
    const float* be1 = (const float*)d_in[14];
    const float* g2  = (const float*)d_in[15];
    const float* be2 = (const float*)d_in[16];

    const size_t MiB = 1ull << 20;
    char* w = (char*)d_ws;
    float* hm   = (float*)w;                      // 8 KB
    u16* Hb    = (u16*)(w + 1 * MiB);             // 16 MiB
    u16* Wqkvt = (u16*)(w + 17 * MiB);            // 1.5 MiB [Wq^T|Wk^T|Wv^T]
    u16* W1t   = (u16*)(w + 18 * MiB + 512 * 1024); // 1 MiB
    u16* W2t   = (u16*)(w + 19 * MiB + 512 * 1024); // 1 MiB
    u16* Q     = (u16*)(w + 21 * MiB);            // 16 MiB
    u16* Kb    = (u16*)(w + 37 * MiB);            // 16 MiB
    u16* Vt    = (u16*)(w + 53 * MiB);            // 16 MiB  [b][512][2048]
    u16* AO    = (u16*)(w + 69 * MiB);            // 16 MiB
    u16* HID   = (u16*)(w + 85 * MiB);            // 32 MiB -> total 117 MiB
    // aliases (lifetimes disjoint):
    u16* X   = Kb;   // LN1 output (K dead after attention)
    u16* F2  = Vt;   // ffn2 output (V dead after attention)

    const int BN = 8, N = SEQN, D = DHID;

    // fp32 -> bf16 conversions (weights transposed, QKV concatenated)
    cvt_kernel<<<(BN * N * D) / (8 * 256), 256, 0, stream>>>(H, Hb, BN * N * D);
    cvt_t_kernel<<<(D * D + 255) / 256, 256, 0, stream>>>(Wq, Wqkvt, D, D);
    cvt_t_kernel<<<(D * D + 255) / 256, 256, 0, stream>>>(Wk, Wqkvt + D * D, D, D);
    cvt_t_kernel<<<(D * D + 255) / 256, 256, 0, stream>>>(Wv, Wqkvt + 2 * D * D, D, D);
    cvt_t_kernel<<<(D * 2 * D + 255) / 256, 256, 0, stream>>>(W1, W1t, D, 2 * D);
    cvt_t_kernel<<<(2 * D * D + 255) / 256, 256, 0, stream>>>(W2, W2t, 2 * D, D);

    hmean_kernel<<<N, 64, 0, stream>>>(hop, hm);

    // fused QKV: C[16384,1536] over [Q|K|Vt] outputs
    gemm_bt<EPI_QKV><<<dim3(12, 128, 1), 256, 0, stream>>>(
        Hb, Wqkvt, nullptr, nullptr, D, D, D, 0, Q, Kb, Vt, bq, bk, bv);

    // fused attention: 512 blocks (8 batches x 64 stripes of 32 rows), 2/CU
    attn_kernel<<<dim3(8, 64), 256, 65536, stream>>>(Q, Kb, Vt, adj, hm, AO);

    // x = LN(attn_out + H)
    ln_hf32_kernel<<<BN * N, 256, 0, stream>>>(AO, H, g1, be1, X);

    // hid = relu(x @ W1 + b1)
    gemm_bt<EPI_RELU><<<dim3(8, 128, 1), 256, 0, stream>>>(
        X, W1t, HID, b1, D, D, D, 2 * D, nullptr, nullptr, nullptr, nullptr, nullptr, nullptr);

    // f2 = hid @ W2 + b2
    gemm_bt<EPI_BIAS><<<dim3(4, 128, 1), 256, 0, stream>>>(
        HID, W2t, F2, b2, 2 * D, 2 * D, 2 * D, D, nullptr, nullptr, nullptr, nullptr, nullptr, nullptr);

    // out = LN(f2 + x)  -> fp32 d_out
    ln_kernel_f32out<<<BN * N, 256, 0, stream>>>(F2, X, g2, be2, (float*)d_out);
}